// Round 18
// baseline (216.693 us; speedup 1.0000x reference)
//
#include <hip/hip_runtime.h>
#include <hip/hip_bf16.h>

typedef unsigned short ush;
typedef __bf16 v8bf __attribute__((ext_vector_type(8)));
typedef float f32x4 __attribute__((ext_vector_type(4)));
typedef float f32x16 __attribute__((ext_vector_type(16)));

#define SPD 56           // input spatial dim
#define OSD 52           // output spatial dim
#define SP3 175616       // 56^3
#define NCX 5488         // conv_x blocks: 2744 spatial-chunks x 2 cg
// Compact-A: 44 of 125 taps have A==0 (emb==0 when d^2>=1.5625). Active taps = 81,
// padded to 88 = 4 waves x 22. A rows = 2cg x 88 + 1 prefetch-overrun row = 177.
#define NTAP 88
#define NROW 177
#define N_A_ELEMS (NROW*2048)  // 362496
#define NBA (N_A_ELEMS/256)    // 1416
#define VBT_OFF 393216         // ush offset of vbt[] inside ws (768KB byte offset)

// direct global->LDS DMA: wave-uniform LDS base + lane*16, per-lane global src
#define GLD_LDS(gp, lp) __builtin_amdgcn_global_load_lds( \
    (const __attribute__((address_space(1))) void*)(gp),  \
    (__attribute__((address_space(3))) void*)(lp), 16, 0, 0)

__device__ __forceinline__ int tap_active(int tau) {
    int dz = tau / 25, dy = (tau / 5) % 5, dx = tau % 5;
    int e = (dz == 0 || dz == 4) + (dy == 0 || dy == 4) + (dx == 0 || dx == 4);
    return e < 2;
}

// ---------------- kernel 1: fused aux — conv_x transpose + build_A (compact) -----------
__global__ void aux_kernel(const float* __restrict__ x, ush* __restrict__ xb,
                           const float* __restrict__ weight, const float* __restrict__ w_sc0,
                           const float* __restrict__ w_sc1, ush* __restrict__ A,
                           ush* __restrict__ vbt) {
    __shared__ float t[64 * 33];
    const int bid = blockIdx.x;
    const int tid = threadIdx.x;
    if (bid < NCX) {
        // ---- conv_x: x fp32 [c64][s] -> bf16 [cg2][s][c32] via LDS transpose ----
        const int s0 = (bid % 2744) * 64;
        const int cg = bid / 2744;
        const int w = tid >> 6, l = tid & 63;
        #pragma unroll
        for (int k = 0; k < 8; k++) {
            int c = w * 8 + k;
            t[l * 33 + c] = x[(cg * 32 + c) * SP3 + s0 + l];
        }
        __syncthreads();
        int v = tid >> 2, qq = tid & 3;
        union { ush u[8]; uint4 q4; } pk;
        #pragma unroll
        for (int j = 0; j < 8; j++) {
            __hip_bfloat16 b = __float2bfloat16(t[v * 33 + qq * 8 + j]);
            pk.u[j] = *(ush*)&b;
        }
        *(uint4*)(xb + ((size_t)(cg * SP3 + s0 + v)) * 32 + qq * 8) = pk.q4;
        return;
    }
    // ---- vbt table: voxel-base per compact tap slot (pad slots -> 0) ----
    if (bid == NCX && tid < 90) {
        int vb = 0;
        if (tid < 81) {
            int cnt = 0;
            for (int tt = 0; tt < 125; tt++) {
                if (tap_active(tt)) {
                    if (cnt == tid) { vb = (tt / 25) * 64 + ((tt / 5) % 5) * 8 + (tt % 5); break; }
                    cnt++;
                }
            }
        }
        vbt[tid] = (ush)vb;
    }
    // ---- build_A: A[T'][o][c] bf16, T' = cg*88 + tidx (compact active-tap order) ----
    int f = (bid - NCX) * 256 + tid;
    if (f >= N_A_ELEMS) return;
    int c    = f & 31;
    int o    = (f >> 5) & 63;
    int T    = f >> 11;             // 0..176
    int cg   = (T >= NTAP) ? 1 : 0; // row 176 -> tidx 88 -> pad
    int tidx = T - cg * NTAP;
    if (tidx >= 81) { A[f] = 0; return; }
    // map compact tidx -> tau by scanning active taps
    int tau = 0, cnt = 0;
    for (int tt = 0; tt < 125; tt++) {
        if (tap_active(tt)) {
            if (cnt == tidx) { tau = tt; break; }
            cnt++;
        }
    }
    int i   = cg * 32 + c;
    int dz = tau / 25, dy = (tau / 5) % 5, dx = tau % 5;
    float rz = -1.f + 0.5f * dz, ry = -1.f + 0.5f * dy, rx = -1.f + 0.5f * dx;
    float d = sqrtf(rz * rz + ry * ry + rx * rx);
    float dm = fmaxf(d, 1e-12f);
    float nv[3] = { rz / dm, ry / dm, rx / dm };
    float emb[5];
    #pragma unroll
    for (int m = 0; m < 5; m++) {
        float diff = 4.f * d - (float)m;
        float ta = diff + 1.f, tb = 1.f - diff;
        float sa = ta > 0.f ? expf(-1.f / ta) : 0.f;
        float sb = tb > 0.f ? expf(-1.f / tb) : 0.f;
        emb[m] = 1.14136f * 7.3890560989306495f * sa * sb;
    }
    const float PW0 = 0.17677669529663687f;
    const float PW1 = 0.30618621784789724f;
    const float IS3 = 0.57735026918962576f;
    float val = 0.f;
    int widx = -1; float scale = 0.f;
    if (i < 16) {
        if (o < 16) { widx = i * 16 + o;                         scale = PW0; }
        else        { int wc = (o - 16) / 3, kc = (o - 16) % 3;
                      widx = 256 + i * 16 + wc;                  scale = PW1 * nv[kc]; }
    } else {
        int u = (i - 16) / 3, ic = (i - 16) % 3;
        if (o < 16) { widx = 768 + u * 16 + o;                   scale = PW0 * nv[ic]; }
        else        { int wc = (o - 16) / 3, jc = (o - 16) % 3;
                      if (ic == jc) { widx = 512 + u * 16 + wc;  scale = PW1 * IS3; } }
    }
    if (widx >= 0) {
        float wv = 0.f;
        #pragma unroll
        for (int m = 0; m < 5; m++) wv += emb[m] * weight[m * 1024 + widx];
        val = scale * wv;
    }
    if (tau == 62) {
        if (i < 16 && o < 16) val += 0.25f * w_sc0[i * 16 + o];
        else if (i >= 16 && o >= 16) {
            int u = (i - 16) / 3, ic = (i - 16) % 3;
            int wc = (o - 16) / 3, jc = (o - 16) % 3;
            if (ic == jc) val += 0.25f * w_sc1[u * 16 + wc];
        }
    }
    __hip_bfloat16 b = __float2bfloat16(val);
    A[f] = *(ush*)&b;
}

// ---------------- kernel 2: main conv ---------------------------------------------------
// RETILE (R17 lesson): occupancy 18.4% == 77% round-fill x 25%: 1184 blocks / 512
// resident = 2.31 -> quantizes to 3 rounds, tail round 31% full. New tile 4x4x6 ->
// 13x13x9 = 1521 blocks = 2.97 rounds (99% fill, same 3 rounds, 28% more blocks).
// Per block: acc 2mt x 3nt = 96 regs, 12 MFMA + 6 ds_read per slot, staging 10
// z-slices = 40 KB, epilogue red 2x6 frags = 48 KB -> LDS 48 KB. z-pad waste drops
// (9x6=54 vs 7x8=56 slices). Keeps: compact-A 88 slots, full-tap B read-ahead,
// global_load_lds staging, XOR-swizzled epilogue (R17: conflicts 5.45M -> 0.6M).
__launch_bounds__(256, 2)
__global__ void conv_main(const ush* __restrict__ A, const ush* __restrict__ vbt,
                          const ush* __restrict__ xb, float* __restrict__ out) {
    __shared__ ush patch[24576];   // 48 KB: staging 40 KB, epilogue red 48 KB

    const int b  = blockIdx.x;
    const int bp = (b & 7) * 191 + (b >> 3);   // XCD-contiguous slab mapping (8 x 191)
    if (bp >= 1521) return;
    const int bx = bp % 13;
    const int t1 = bp / 13;
    const int by = t1 % 13;
    const int bz = t1 / 13;                    // 0..8
    const int x0 = bx * 4, y0 = by * 4;
    const int z0 = (bz == 8) ? 46 : bz * 6;    // last tile overlaps (rewrites same vals)

    const int tid  = threadIdx.x;
    const int wv   = tid >> 6;
    const int lane = tid & 63;
    const int lhi  = lane >> 5;                // k-group for A/B operands
    // B col = lane&31 -> px (zloc = (l>>4)&1, y = (l>>2)&3, x = l&3)
    const int rbase32 = ((lane >> 4) & 1) * 64 + ((lane >> 2) & 3) * 8 + (lane & 3);
    const int t0 = wv * 22;                    // 22 tap-slots per wave
    const int ssw = (lane >> 1) & 3;           // epilogue bank-spread XOR

    f32x16 acc[2][3];
    #pragma unroll
    for (int mt = 0; mt < 2; mt++)
        #pragma unroll
        for (int nt = 0; nt < 3; nt++)
            acc[mt][nt] = (f32x16)(0.f);

    v8bf afA[2][2], afB[2][2];                 // A dbuf: [mt][h]
    v8bf b0A[3], b0B[3], b1A[3], b1B[3];       // B: h0/h1 x parity (peak live = 3 sets)

    auto SLOTS = [&](int vb, int& s0, int& s1) {
        int v0 = vb + rbase32;
        int pre = v0 + (v0 >> 3);
        s0 = v0 * 4 + ((lhi + pre) & 3);
        s1 = v0 * 4 + ((2 + lhi + pre) & 3);
    };
    auto LDB = [&](v8bf (&bf)[3], int slot) {
        #pragma unroll
        for (int nt = 0; nt < 3; nt++)
            bf[nt] = *(const v8bf*)(patch + slot * 8 + nt * 4096);
    };
    auto LDA = [&](v8bf (&af)[2][2], const ush* p) {
        #pragma unroll
        for (int mt = 0; mt < 2; mt++)
            #pragma unroll
            for (int h = 0; h < 2; h++)
                af[mt][h] = *(const v8bf*)(p + mt * 1024 + h * 16);
    };
    auto MM0 = [&](v8bf (&af)[2][2], v8bf (&bf)[3]) {
        #pragma unroll
        for (int mt = 0; mt < 2; mt++)
            #pragma unroll
            for (int nt = 0; nt < 3; nt++)
                acc[mt][nt] = __builtin_amdgcn_mfma_f32_32x32x16_bf16(af[mt][0], bf[nt], acc[mt][nt], 0, 0, 0);
    };
    auto MM1 = [&](v8bf (&af)[2][2], v8bf (&bf)[3]) {
        #pragma unroll
        for (int mt = 0; mt < 2; mt++)
            #pragma unroll
            for (int nt = 0; nt < 3; nt++)
                acc[mt][nt] = __builtin_amdgcn_mfma_f32_32x32x16_bf16(af[mt][1], bf[nt], acc[mt][nt], 0, 0, 0);
    };

    for (int cg = 0; cg < 2; cg++) {
        const ush* Ap = A + ((size_t)(cg * NTAP + t0)) * 2048 + (lane & 31) * 32 + lhi * 8;
        LDA(afA, Ap);                          // A(tap t0): prefetch hides under staging
        int vb0 = vbt[t0];                     // vb of tap t0 (broadcast)
        int vbn = vbt[t0 + 1];                 // vb of tap t0+1

        __syncthreads();
        // stage this cg via global_load_lds: 10 z-slices x 64 vox x 32ch = 2560 chunks,
        // linear LDS dest (uniform base + lane*16), inverse-swizzled global src.
        #pragma unroll
        for (int it = 0; it < 10; it++) {
            int slot = it * 256 + wv * 64 + lane;
            int r    = slot & 3;
            int vox  = slot >> 2;
            int qq   = (r - vox - (vox >> 3)) & 3;
            int xp = vox & 7, yp = (vox >> 3) & 7, zp = vox >> 6;   // zp in [0,10)
            const ush* g = xb + ((size_t)((cg * SPD + z0 + zp) * SPD + (y0 + yp)) * SPD + (x0 + xp)) * 32 + qq * 8;
            GLD_LDS(g, patch + (size_t)(it * 256 + wv * 64) * 8);
        }
        __syncthreads();

        // ---- pipelined K loop: wave wv owns tap-slots [t0, t0+22), full-tap read-ahead ----
        int s0, s1;
        SLOTS(vb0, s0, s1);                    // slots of tap t0
        LDB(b0A, s0);                          // h0(t0)
        LDB(b1A, s1);                          // h1(t0)

        #pragma unroll 1
        for (int j = 0; j < 22; j += 2) {
            // --- tap j (A in afA, B in b0A/b1A); vbn = vb of tap j+1 ---
            SLOTS(vbn, s0, s1);                // slots of tap j+1
            LDB(b0B, s0);                      // h0(j+1): covered by MM0(j)+MM1(j)
            LDA(afB, Ap + 2048);               // A(j+1)
            MM0(afA, b0A);
            LDB(b1B, s1);                      // h1(j+1)
            MM1(afA, b1A);
            vbn = vbt[t0 + j + 2];             // vb of tap j+2 (max idx 88 < 90)
            Ap += 2048;
            // --- tap j+1 (A in afB, B in b0B/b1B) ---
            SLOTS(vbn, s0, s1);                // slots of tap j+2
            LDB(b0A, s0);
            LDA(afA, Ap + 2048);               // A(j+2) (final overrun lands in zeroed row 176)
            MM0(afB, b0B);
            LDB(b1A, s1);
            MM1(afB, b1B);
            vbn = vbt[t0 + j + 3];             // vb of tap j+3 (max idx 89 < 90)
            Ap += 2048;
        }
    }

    // ---- cross-wave reduction: red[writer(2)][frag(6)][lane][16] = 48 KB, XOR-swizzled ----
    __syncthreads();
    float* red = (float*)patch;
    if (wv >= 2) {
        #pragma unroll
        for (int mt = 0; mt < 2; mt++)
            #pragma unroll
            for (int nt = 0; nt < 3; nt++) {
                float* p = red + (wv - 2) * 6144 + (mt * 3 + nt) * 1024 + lane * 16;
                #pragma unroll
                for (int s = 0; s < 4; s++) {
                    f32x4 v = { acc[mt][nt][s*4+0], acc[mt][nt][s*4+1], acc[mt][nt][s*4+2], acc[mt][nt][s*4+3] };
                    *(f32x4*)(p + (s ^ ssw) * 4) = v;
                }
            }
    }
    __syncthreads();
    if (wv < 2) {
        #pragma unroll
        for (int mt = 0; mt < 2; mt++)
            #pragma unroll
            for (int nt = 0; nt < 3; nt++) {
                float* p = red + wv * 6144 + (mt * 3 + nt) * 1024 + lane * 16;
                #pragma unroll
                for (int s = 0; s < 4; s++) {
                    f32x4 v = *(const f32x4*)(p + (s ^ ssw) * 4);
                    f32x4 m = { acc[mt][nt][s*4+0], acc[mt][nt][s*4+1], acc[mt][nt][s*4+2], acc[mt][nt][s*4+3] };
                    *(f32x4*)(p + (s ^ ssw) * 4) = v + m;
                }
            }
    }
    __syncthreads();

    // store: 6 frags; waves 0,1,2 store 2 each (fi = wv*2+k, guard fi<6); final = half0+half1
    const int yy = y0 + ((lane >> 2) & 3);
    const int xx = x0 + (lane & 3);
    #pragma unroll
    for (int k = 0; k < 2; k++) {
        int fi = wv * 2 + k;
        if (fi < 6) {
            int mt = fi / 3, nt = fi % 3;
            int zz = z0 + nt * 2 + ((lane >> 4) & 1);
            #pragma unroll
            for (int s = 0; s < 4; s++) {
                f32x4 v = *(const f32x4*)(red + fi * 1024 + lane * 16 + (s ^ ssw) * 4);
                v += *(const f32x4*)(red + 6144 + fi * 1024 + lane * 16 + (s ^ ssw) * 4);
                #pragma unroll
                for (int e = 0; e < 4; e++) {
                    int o = mt * 32 + e + 8 * s + 4 * lhi;
                    out[((o * OSD + zz) * OSD + yy) * OSD + xx] = v[e];
                }
            }
        }
    }
}

extern "C" void kernel_launch(void* const* d_in, const int* in_sizes, int n_in,
                              void* d_out, int out_size, void* d_ws, size_t ws_size,
                              hipStream_t stream) {
    const float* x      = (const float*)d_in[0];
    const float* weight = (const float*)d_in[1];
    const float* w_sc0  = (const float*)d_in[2];
    const float* w_sc1  = (const float*)d_in[3];
    float* out = (float*)d_out;

    ush* A   = (ush*)d_ws;                              // 177 rows x 2048 ush = 725 KB
    ush* vbt = A + VBT_OFF;                             // 90 ush at 768 KB offset
    ush* xb  = (ush*)((char*)d_ws + (2 << 20));         // 22.5 MB

    aux_kernel<<<NCX + NBA, 256, 0, stream>>>(x, xb, weight, w_sc0, w_sc1, A, vbt);
    conv_main<<<1528, 256, 0, stream>>>(A, vbt, xb, out);
}

// Round 19
// 193.229 us; speedup vs baseline: 1.1214x; 1.1214x over previous
//
#include <hip/hip_runtime.h>
#include <hip/hip_bf16.h>

typedef unsigned short ush;
typedef __bf16 v8bf __attribute__((ext_vector_type(8)));
typedef float f32x4 __attribute__((ext_vector_type(4)));
typedef float f32x16 __attribute__((ext_vector_type(16)));

#define SPD 56           // input spatial dim
#define OSD 52           // output spatial dim
#define SP3 175616       // 56^3
#define NCX2 1372        // conv_x blocks: 686 s-chunks(256) x 2 cg
// Compact-A: 44 of 125 taps have A==0 (emb==0 when d^2>=1.5625). Active taps = 81,
// padded to 88 = 4 waves x 22. A rows = 2cg x 88 + 1 prefetch-overrun row = 177.
#define NTAP 88
#define NROW 177
#define N_A_ELEMS (NROW*2048)  // 362496
#define NBA (N_A_ELEMS/256)    // 1416
#define VBT_OFF 393216         // ush offset of vbt[] inside ws (768KB byte offset)

// the 81 active taps (increasing tau): >=2 coords in {0,4} excluded
__device__ const unsigned char TAU81[81] = {
      6,  7,  8, 11, 12, 13, 16, 17, 18,
     26, 27, 28, 30, 31, 32, 33, 34, 35, 36, 37, 38, 39, 40, 41, 42, 43, 44, 46, 47, 48,
     51, 52, 53, 55, 56, 57, 58, 59, 60, 61, 62, 63, 64, 65, 66, 67, 68, 69, 71, 72, 73,
     76, 77, 78, 80, 81, 82, 83, 84, 85, 86, 87, 88, 89, 90, 91, 92, 93, 94, 96, 97, 98,
    106,107,108,111,112,113,116,117,118 };

// direct global->LDS DMA: wave-uniform LDS base + lane*16, per-lane global src
#define GLD_LDS(gp, lp) __builtin_amdgcn_global_load_lds( \
    (const __attribute__((address_space(1))) void*)(gp),  \
    (__attribute__((address_space(3))) void*)(lp), 16, 0, 0)

// ---------------- kernel 1: fused aux — conv_x transpose + build_A (compact) -----------
__global__ void aux_kernel(const float* __restrict__ x, ush* __restrict__ xb,
                           const float* __restrict__ weight, const float* __restrict__ w_sc0,
                           const float* __restrict__ w_sc1, ush* __restrict__ A,
                           ush* __restrict__ vbt) {
    __shared__ float t[32 * 261];   // 33.4 KB, pad 261 (8*261%32=8 -> quad-conflict-free)
    const int bid = blockIdx.x;
    const int tid = threadIdx.x;
    if (bid < NCX2) {
        // ---- conv_x: x fp32 [c64][s] -> bf16 [cg2][s][c32], 256 s-positions/block ----
        const int s0 = (bid % 686) * 256;
        const int cg = bid / 686;
        const int w = tid >> 6, l = tid & 63;
        #pragma unroll
        for (int k = 0; k < 8; k++) {
            int c = w * 8 + k;
            f32x4 v4 = *(const f32x4*)&x[(size_t)(cg * 32 + c) * SP3 + s0 + l * 4];
            *(f32x4*)&t[c * 261 + l * 4] = v4;
        }
        __syncthreads();
        int qq = tid & 3, vb_ = tid >> 2;
        #pragma unroll
        for (int r = 0; r < 4; r++) {
            int v = vb_ + r * 64;
            union { ush u[8]; uint4 q4; } pk;
            #pragma unroll
            for (int j = 0; j < 8; j++) {
                __hip_bfloat16 b = __float2bfloat16(t[(qq * 8 + j) * 261 + v]);
                pk.u[j] = *(ush*)&b;
            }
            *(uint4*)(xb + ((size_t)(cg * SP3 + s0 + v)) * 32 + qq * 8) = pk.q4;
        }
        return;
    }
    // ---- vbt table: voxel-base per compact tap slot (pad slots -> 0) ----
    if (bid == NCX2 && tid < 90) {
        int vb = 0;
        if (tid < 81) {
            int tt = TAU81[tid];
            vb = (tt / 25) * 64 + ((tt / 5) % 5) * 8 + (tt % 5);
        }
        vbt[tid] = (ush)vb;
    }
    // ---- build_A: A[T'][o][c] bf16, T' = cg*88 + tidx (compact active-tap order) ----
    int f = (bid - NCX2) * 256 + tid;
    if (f >= N_A_ELEMS) return;
    int c    = f & 31;
    int o    = (f >> 5) & 63;
    int T    = f >> 11;             // 0..176
    int cg   = (T >= NTAP) ? 1 : 0; // row 176 -> tidx 88 -> pad
    int tidx = T - cg * NTAP;
    if (tidx >= 81) { A[f] = 0; return; }
    int tau = TAU81[tidx];          // block-uniform -> scalar load (replaces 125-scan)
    int i   = cg * 32 + c;
    int dz = tau / 25, dy = (tau / 5) % 5, dx = tau % 5;
    float rz = -1.f + 0.5f * dz, ry = -1.f + 0.5f * dy, rx = -1.f + 0.5f * dx;
    float d = sqrtf(rz * rz + ry * ry + rx * rx);
    float dm = fmaxf(d, 1e-12f);
    float nv[3] = { rz / dm, ry / dm, rx / dm };
    float emb[5];
    #pragma unroll
    for (int m = 0; m < 5; m++) {
        float diff = 4.f * d - (float)m;
        float ta = diff + 1.f, tb = 1.f - diff;
        float sa = ta > 0.f ? expf(-1.f / ta) : 0.f;
        float sb = tb > 0.f ? expf(-1.f / tb) : 0.f;
        emb[m] = 1.14136f * 7.3890560989306495f * sa * sb;
    }
    const float PW0 = 0.17677669529663687f;
    const float PW1 = 0.30618621784789724f;
    const float IS3 = 0.57735026918962576f;
    float val = 0.f;
    int widx = -1; float scale = 0.f;
    if (i < 16) {
        if (o < 16) { widx = i * 16 + o;                         scale = PW0; }
        else        { int wc = (o - 16) / 3, kc = (o - 16) % 3;
                      widx = 256 + i * 16 + wc;                  scale = PW1 * nv[kc]; }
    } else {
        int u = (i - 16) / 3, ic = (i - 16) % 3;
        if (o < 16) { widx = 768 + u * 16 + o;                   scale = PW0 * nv[ic]; }
        else        { int wc = (o - 16) / 3, jc = (o - 16) % 3;
                      if (ic == jc) { widx = 512 + u * 16 + wc;  scale = PW1 * IS3; } }
    }
    if (widx >= 0) {
        float wv = 0.f;
        #pragma unroll
        for (int m = 0; m < 5; m++) wv += emb[m] * weight[m * 1024 + widx];
        val = scale * wv;
    }
    if (tau == 62) {
        if (i < 16 && o < 16) val += 0.25f * w_sc0[i * 16 + o];
        else if (i >= 16 && o >= 16) {
            int u = (i - 16) / 3, ic = (i - 16) % 3;
            int wc = (o - 16) / 3, jc = (o - 16) % 3;
            if (ic == jc) val += 0.25f * w_sc1[u * 16 + wc];
        }
    }
    __hip_bfloat16 b = __float2bfloat16(val);
    A[f] = *(ush*)&b;
}

// ---------------- kernel 2: main conv (R17 config, measured 108.5 us) -------------------
// 1184 blocks (flat, XCD-swizzled) = 13x13x7 tiles; block 256 = 4 waves.
// Each wave: 64 oc x 128 px, 32x32x16 MFMA, compact K (88 slots = 81 active + 7 pad).
// R18 lesson: K-loop is per-slot LATENCY-bound (~0.82 us/slot regardless of 12 vs 16
// MFMA/slot); retiling to smaller nt regressed. This config is the measured optimum.
// Keeps: full-tap B read-ahead, global_load_lds staging (linear dest, inv-swizzled src),
// XOR-swizzled epilogue (conflicts 5.45M -> 0.6M in R17).
__launch_bounds__(256, 2)
__global__ void conv_main(const ush* __restrict__ A, const ush* __restrict__ vbt,
                          const ush* __restrict__ xb, float* __restrict__ out) {
    __shared__ ush patch[32768];   // 64 KB: staging 48 KB, epilogue red 64 KB

    const int b  = blockIdx.x;
    const int bp = (b & 7) * 148 + (b >> 3);   // XCD-contiguous slab mapping
    if (bp >= 1183) return;
    const int bx = bp % 13;
    const int t1 = bp / 13;
    const int by = t1 % 13;
    const int bz = t1 / 13;                    // 0..6
    const int x0 = bx * 4, y0 = by * 4;
    const int z0 = (bz == 6) ? 44 : bz * 8;

    const int tid  = threadIdx.x;
    const int wv   = tid >> 6;
    const int lane = tid & 63;
    const int lhi  = lane >> 5;                // k-group for A/B operands
    // B col = lane&31 -> px (zloc = (l>>4)&1, y = (l>>2)&3, x = l&3)
    const int rbase32 = ((lane >> 4) & 1) * 64 + ((lane >> 2) & 3) * 8 + (lane & 3);
    const int t0 = wv * 22;                    // 22 tap-slots per wave
    const int ssw = (lane >> 1) & 3;           // epilogue bank-spread XOR

    f32x16 acc[2][4];
    #pragma unroll
    for (int mt = 0; mt < 2; mt++)
        #pragma unroll
        for (int nt = 0; nt < 4; nt++)
            acc[mt][nt] = (f32x16)(0.f);

    v8bf afA[2][2], afB[2][2];                 // A dbuf: [mt][h]
    v8bf b0A[4], b0B[4], b1A[4], b1B[4];       // B: h0/h1 x parity (peak live = 3 sets)

    auto SLOTS = [&](int vb, int& s0, int& s1) {
        int v0 = vb + rbase32;
        int pre = v0 + (v0 >> 3);
        s0 = v0 * 4 + ((lhi + pre) & 3);
        s1 = v0 * 4 + ((2 + lhi + pre) & 3);
    };
    auto LDB = [&](v8bf (&bf)[4], int slot) {
        #pragma unroll
        for (int nt = 0; nt < 4; nt++)
            bf[nt] = *(const v8bf*)(patch + slot * 8 + nt * 4096);
    };
    auto LDA = [&](v8bf (&af)[2][2], const ush* p) {
        #pragma unroll
        for (int mt = 0; mt < 2; mt++)
            #pragma unroll
            for (int h = 0; h < 2; h++)
                af[mt][h] = *(const v8bf*)(p + mt * 1024 + h * 16);
    };
    auto MM0 = [&](v8bf (&af)[2][2], v8bf (&bf)[4]) {
        #pragma unroll
        for (int mt = 0; mt < 2; mt++)
            #pragma unroll
            for (int nt = 0; nt < 4; nt++)
                acc[mt][nt] = __builtin_amdgcn_mfma_f32_32x32x16_bf16(af[mt][0], bf[nt], acc[mt][nt], 0, 0, 0);
    };
    auto MM1 = [&](v8bf (&af)[2][2], v8bf (&bf)[4]) {
        #pragma unroll
        for (int mt = 0; mt < 2; mt++)
            #pragma unroll
            for (int nt = 0; nt < 4; nt++)
                acc[mt][nt] = __builtin_amdgcn_mfma_f32_32x32x16_bf16(af[mt][1], bf[nt], acc[mt][nt], 0, 0, 0);
    };

    for (int cg = 0; cg < 2; cg++) {
        const ush* Ap = A + ((size_t)(cg * NTAP + t0)) * 2048 + (lane & 31) * 32 + lhi * 8;
        LDA(afA, Ap);                          // A(tap t0): prefetch hides under staging
        int vb0 = vbt[t0];                     // vb of tap t0 (broadcast)
        int vbn = vbt[t0 + 1];                 // vb of tap t0+1

        __syncthreads();
        // stage this cg via global_load_lds: linear LDS dest (uniform base + lane*16),
        // inverse-swizzled global src; LDS image identical to the R14 swizzled layout.
        #pragma unroll
        for (int it = 0; it < 12; it++) {
            int slot = it * 256 + wv * 64 + lane;
            int r    = slot & 3;
            int vox  = slot >> 2;
            int qq   = (r - vox - (vox >> 3)) & 3;
            int xp = vox & 7, yp = (vox >> 3) & 7, zp = vox >> 6;   // zp in [0,12)
            const ush* g = xb + ((size_t)((cg * SPD + z0 + zp) * SPD + (y0 + yp)) * SPD + (x0 + xp)) * 32 + qq * 8;
            GLD_LDS(g, patch + (size_t)(it * 256 + wv * 64) * 8);
        }
        __syncthreads();

        // ---- pipelined K loop: wave wv owns tap-slots [t0, t0+22), full-tap read-ahead ----
        int s0, s1;
        SLOTS(vb0, s0, s1);                    // slots of tap t0
        LDB(b0A, s0);                          // h0(t0)
        LDB(b1A, s1);                          // h1(t0)

        #pragma unroll 1
        for (int j = 0; j < 22; j += 2) {
            // --- tap j (A in afA, B in b0A/b1A); vbn = vb of tap j+1 ---
            SLOTS(vbn, s0, s1);                // slots of tap j+1
            LDB(b0B, s0);                      // h0(j+1): cover = MM0(j)+MM1(j)
            LDA(afB, Ap + 2048);               // A(j+1)
            MM0(afA, b0A);
            LDB(b1B, s1);                      // h1(j+1)
            MM1(afA, b1A);
            vbn = vbt[t0 + j + 2];             // vb of tap j+2 (max idx 88 < 90)
            Ap += 2048;
            // --- tap j+1 (A in afB, B in b0B/b1B) ---
            SLOTS(vbn, s0, s1);                // slots of tap j+2
            LDB(b0A, s0);
            LDA(afA, Ap + 2048);               // A(j+2) (final overrun lands in zeroed row 176)
            MM0(afB, b0B);
            LDB(b1A, s1);
            MM1(afB, b1B);
            vbn = vbt[t0 + j + 3];             // vb of tap j+3 (max idx 89 < 90)
            Ap += 2048;
        }
    }

    // ---- cross-wave reduction: red[writer][frag8][lane][16] = 64 KB, XOR-swizzled ----
    // physical slot for logical s is s^ssw -> 8 consecutive lanes cover all 32 banks.
    __syncthreads();
    float* red = (float*)patch;
    if (wv >= 2) {
        #pragma unroll
        for (int mt = 0; mt < 2; mt++)
            #pragma unroll
            for (int nt = 0; nt < 4; nt++) {
                float* p = red + (wv - 2) * 8192 + (mt * 4 + nt) * 1024 + lane * 16;
                #pragma unroll
                for (int s = 0; s < 4; s++) {
                    f32x4 v = { acc[mt][nt][s*4+0], acc[mt][nt][s*4+1], acc[mt][nt][s*4+2], acc[mt][nt][s*4+3] };
                    *(f32x4*)(p + (s ^ ssw) * 4) = v;
                }
            }
    }
    __syncthreads();
    if (wv < 2) {
        #pragma unroll
        for (int mt = 0; mt < 2; mt++)
            #pragma unroll
            for (int nt = 0; nt < 4; nt++) {
                float* p = red + wv * 8192 + (mt * 4 + nt) * 1024 + lane * 16;
                #pragma unroll
                for (int s = 0; s < 4; s++) {
                    f32x4 v = *(const f32x4*)(p + (s ^ ssw) * 4);
                    f32x4 m = { acc[mt][nt][s*4+0], acc[mt][nt][s*4+1], acc[mt][nt][s*4+2], acc[mt][nt][s*4+3] };
                    *(f32x4*)(p + (s ^ ssw) * 4) = v + m;
                }
            }
    }
    __syncthreads();

    // store: 8 frags total; wave wv stores frags {2wv, 2wv+1}; final = half0 + half1
    const int yy = y0 + ((lane >> 2) & 3);
    const int xx = x0 + (lane & 3);
    #pragma unroll
    for (int k = 0; k < 2; k++) {
        int fi = wv * 2 + k;
        int mt = fi >> 2, nt = fi & 3;
        int zz = z0 + nt * 2 + ((lane >> 4) & 1);
        #pragma unroll
        for (int s = 0; s < 4; s++) {
            f32x4 v = *(const f32x4*)(red + fi * 1024 + lane * 16 + (s ^ ssw) * 4);
            v += *(const f32x4*)(red + 8192 + fi * 1024 + lane * 16 + (s ^ ssw) * 4);
            #pragma unroll
            for (int e = 0; e < 4; e++) {
                int o = mt * 32 + e + 8 * s + 4 * lhi;
                out[((o * OSD + zz) * OSD + yy) * OSD + xx] = v[e];
            }
        }
    }
}

extern "C" void kernel_launch(void* const* d_in, const int* in_sizes, int n_in,
                              void* d_out, int out_size, void* d_ws, size_t ws_size,
                              hipStream_t stream) {
    const float* x      = (const float*)d_in[0];
    const float* weight = (const float*)d_in[1];
    const float* w_sc0  = (const float*)d_in[2];
    const float* w_sc1  = (const float*)d_in[3];
    float* out = (float*)d_out;

    ush* A   = (ush*)d_ws;                              // 177 rows x 2048 ush = 725 KB
    ush* vbt = A + VBT_OFF;                             // 90 ush at 768 KB offset
    ush* xb  = (ush*)((char*)d_ws + (2 << 20));         // 22.5 MB

    aux_kernel<<<NCX2 + NBA, 256, 0, stream>>>(x, xb, weight, w_sc0, w_sc1, A, vbt);
    conv_main<<<1184, 256, 0, stream>>>(A, vbt, xb, out);
}